// Round 1
// baseline (82.857 us; speedup 1.0000x reference)
//
#include <hip/hip_runtime.h>
#include <math.h>

#define NROWS 100000
#define DIM 256
#define BB 1024
#define KK 128
#define PITCH 264   // bf16 elements per LDS row: 528 B = 33*16 -> b128 reads cycle 8 slots, 2-way (free)

typedef __attribute__((ext_vector_type(8))) short short8;
typedef __attribute__((ext_vector_type(4))) float float4v;

__device__ __forceinline__ unsigned short f2bf(float x) {
    unsigned u = __float_as_uint(x);
    u += 0x7FFFu + ((u >> 16) & 1u);   // round-to-nearest-even
    return (unsigned short)(u >> 16);
}

// One block per batch element b. 512 threads = 8 waves.
// Phase A: gather 128 rows of text/feature, compute row norms on the fly,
//          stage te_local (bf16) into LDS, accumulate f_diff partial sums.
// Phase B: Gram matrix via MFMA (wave w owns rows w*16..w*16+15 x all 128 cols),
//          in-register gumbel-softmax + s_diff, then final per-block reduce.
__global__ __launch_bounds__(512) void fused_main(
    const float* __restrict__ feature,
    const float* __restrict__ text,
    const float* __restrict__ virt,
    const float* __restrict__ gumbel,
    const int*   __restrict__ ego,
    const int*   __restrict__ adj,
    float*       __restrict__ score_raw)
{
    __shared__ unsigned short tb[KK * PITCH];   // 67584 B
    __shared__ float fpart[8][DIM];             // 8192 B
    __shared__ float spart[8];

    const int b    = blockIdx.x;
    const int tid  = threadIdx.x;
    const int wave = tid >> 6;
    const int lane = tid & 63;

    // lane handles d = 4*lane .. 4*lane+3
    const float4 vv = ((const float4*)virt)[lane];

    float fa0 = 0.f, fa1 = 0.f, fa2 = 0.f, fa3 = 0.f;
    const int* ego_b = ego + b * KK;

    for (int k = wave * 16; k < wave * 16 + 16; ++k) {
        const int e = ego_b[k];
        const float4 t4 = ((const float4*)(text    + (size_t)e * DIM))[lane];
        const float4 f4 = ((const float4*)(feature + (size_t)e * DIM))[lane];

        float st = t4.x*t4.x + t4.y*t4.y + t4.z*t4.z + t4.w*t4.w;
        float sf = f4.x*f4.x + f4.y*f4.y + f4.z*f4.z + f4.w*f4.w;
        #pragma unroll
        for (int m = 1; m < 64; m <<= 1) {
            st += __shfl_xor(st, m);
            sf += __shfl_xor(sf, m);
        }
        const float inv_ne = 1.f / fmaxf(sqrtf(st), 1e-12f);
        const float inv_nf = 1.f / fmaxf(sqrtf(sf), 1e-12f);

        const float ex = t4.x * inv_ne, ey = t4.y * inv_ne;
        const float ez = t4.z * inv_ne, ew = t4.w * inv_ne;
        const float wx = ex - vv.x, wy = ey - vv.y;
        const float wz = ez - vv.z, ww = ew - vv.w;
        float sw = wx*wx + wy*wy + wz*wz + ww*ww;
        #pragma unroll
        for (int m = 1; m < 64; m <<= 1) sw += __shfl_xor(sw, m);
        const float inv_nt = 1.f / fmaxf(sqrtf(sw), 1e-12f);

        fa0 += f4.x * inv_nf - ex;
        fa1 += f4.y * inv_nf - ey;
        fa2 += f4.z * inv_nf - ez;
        fa3 += f4.w * inv_nf - ew;

        ushort4 pk;
        pk.x = f2bf(wx * inv_nt);
        pk.y = f2bf(wy * inv_nt);
        pk.z = f2bf(wz * inv_nt);
        pk.w = f2bf(ww * inv_nt);
        *(ushort4*)&tb[k * PITCH + 4 * lane] = pk;
    }
    fpart[wave][4*lane + 0] = fa0;
    fpart[wave][4*lane + 1] = fa1;
    fpart[wave][4*lane + 2] = fa2;
    fpart[wave][4*lane + 3] = fa3;
    __syncthreads();

    // ---- Phase B: Gram matrix. C[k][j] = sum_d tb[k][d]*tb[j][d].
    // A-frag and B-frag have the same lane layout for 16x16x32 -> one loader.
    float4v acc[8];
    const float4v zero = {0.f, 0.f, 0.f, 0.f};
    #pragma unroll
    for (int t = 0; t < 8; ++t) acc[t] = zero;

    const int g = lane >> 4;   // 0..3
    const int c = lane & 15;   // col within tile / row within frag

    #pragma unroll
    for (int q = 0; q < 8; ++q) {
        const int dq = q * 32 + g * 8;
        const short8 af = *(const short8*)&tb[(wave * 16 + c) * PITCH + dq];
        short8 bf0 = *(const short8*)&tb[(0*16 + c) * PITCH + dq];
        short8 bf1 = *(const short8*)&tb[(1*16 + c) * PITCH + dq];
        short8 bf2 = *(const short8*)&tb[(2*16 + c) * PITCH + dq];
        short8 bf3 = *(const short8*)&tb[(3*16 + c) * PITCH + dq];
        short8 bf4 = *(const short8*)&tb[(4*16 + c) * PITCH + dq];
        short8 bf5 = *(const short8*)&tb[(5*16 + c) * PITCH + dq];
        short8 bf6 = *(const short8*)&tb[(6*16 + c) * PITCH + dq];
        short8 bf7 = *(const short8*)&tb[(7*16 + c) * PITCH + dq];
        acc[0] = __builtin_amdgcn_mfma_f32_16x16x32_bf16(af, bf0, acc[0], 0, 0, 0);
        acc[1] = __builtin_amdgcn_mfma_f32_16x16x32_bf16(af, bf1, acc[1], 0, 0, 0);
        acc[2] = __builtin_amdgcn_mfma_f32_16x16x32_bf16(af, bf2, acc[2], 0, 0, 0);
        acc[3] = __builtin_amdgcn_mfma_f32_16x16x32_bf16(af, bf3, acc[3], 0, 0, 0);
        acc[4] = __builtin_amdgcn_mfma_f32_16x16x32_bf16(af, bf4, acc[4], 0, 0, 0);
        acc[5] = __builtin_amdgcn_mfma_f32_16x16x32_bf16(af, bf5, acc[5], 0, 0, 0);
        acc[6] = __builtin_amdgcn_mfma_f32_16x16x32_bf16(af, bf6, acc[6], 0, 0, 0);
        acc[7] = __builtin_amdgcn_mfma_f32_16x16x32_bf16(af, bf7, acc[7], 0, 0, 0);
    }

    // ---- softmax(sim - 0.5 + gumbel) rows + s_diff, fully in-register.
    // C/D layout: col = t*16 + c, row(local) = g*4 + r   [m89]
    const float* gb = gumbel + (size_t)b * KK * KK;
    const int*   ab = adj    + (size_t)b * KK * KK;
    float rs = 0.f;
    #pragma unroll
    for (int r = 0; r < 4; ++r) {
        const int krow = wave * 16 + g * 4 + r;
        const float* gr = gb + krow * KK + c;
        const int*   ar = ab + krow * KK + c;
        float v[8];
        float mx = -1e30f;
        #pragma unroll
        for (int t = 0; t < 8; ++t) {
            v[t] = acc[t][r] - 0.5f + gr[t * 16];
            mx = fmaxf(mx, v[t]);
        }
        #pragma unroll
        for (int msk = 1; msk < 16; msk <<= 1) mx = fmaxf(mx, __shfl_xor(mx, msk));
        float S = 0.f;
        #pragma unroll
        for (int t = 0; t < 8; ++t) { v[t] = __expf(v[t] - mx); S += v[t]; }
        #pragma unroll
        for (int msk = 1; msk < 16; msk <<= 1) S += __shfl_xor(S, msk);
        const float invS = 1.f / S;
        float T = 0.f;
        #pragma unroll
        for (int t = 0; t < 8; ++t) {
            const float d = (float)ar[t * 16] - v[t] * invS;
            T += d * d;
        }
        #pragma unroll
        for (int msk = 1; msk < 16; msk <<= 1) T += __shfl_xor(T, msk);
        rs += sqrtf(T);   // identical across the 16 lanes of group g
    }
    rs += __shfl_xor(rs, 16);
    rs += __shfl_xor(rs, 32);          // strip total (16 rows)
    if (lane == 0) spart[wave] = rs;
    __syncthreads();

    if (wave == 0) {
        float d0 = 0.f, d1 = 0.f, d2 = 0.f, d3 = 0.f;
        #pragma unroll
        for (int w = 0; w < 8; ++w) {
            d0 += fpart[w][lane];
            d1 += fpart[w][lane + 64];
            d2 += fpart[w][lane + 128];
            d3 += fpart[w][lane + 192];
        }
        const float inv = 1.f / 128.f;
        d0 *= inv; d1 *= inv; d2 *= inv; d3 *= inv;
        float q2 = d0*d0 + d1*d1 + d2*d2 + d3*d3;
        #pragma unroll
        for (int m = 1; m < 64; m <<= 1) q2 += __shfl_xor(q2, m);
        if (lane == 0) {
            float stot = 0.f;
            #pragma unroll
            for (int w = 0; w < 8; ++w) stot += spart[w];
            score_raw[b] = stot * (1.f / 128.f) + sqrtf(q2);
        }
    }
}

__global__ __launch_bounds__(1024) void finalize(
    const float* __restrict__ score_raw,
    const int*   __restrict__ label,
    float*       __restrict__ out)
{
    __shared__ float wmin[16], wmax[16], wsum[16];
    const int tid = threadIdx.x;
    const float s = score_raw[tid];
    float mn = s, mx = s;
    #pragma unroll
    for (int m = 1; m < 64; m <<= 1) {
        mn = fminf(mn, __shfl_xor(mn, m));
        mx = fmaxf(mx, __shfl_xor(mx, m));
    }
    if ((tid & 63) == 0) { wmin[tid >> 6] = mn; wmax[tid >> 6] = mx; }
    __syncthreads();
    float gmn = wmin[0], gmx = wmax[0];
    #pragma unroll
    for (int w = 1; w < 16; ++w) {
        gmn = fminf(gmn, wmin[w]);
        gmx = fmaxf(gmx, wmax[w]);
    }
    const float score = (s - gmn) / (gmx - gmn);
    out[tid] = score;

    const float y  = (float)label[tid];
    const float sc = fminf(fmaxf(score, 1e-7f), 1.f - 1e-7f);
    float term = -(y * logf(sc) + (1.f - y) * log1pf(-sc));
    #pragma unroll
    for (int m = 1; m < 64; m <<= 1) term += __shfl_xor(term, m);
    if ((tid & 63) == 0) wsum[tid >> 6] = term;
    __syncthreads();
    if (tid == 0) {
        float tot = 0.f;
        #pragma unroll
        for (int w = 0; w < 16; ++w) tot += wsum[w];
        out[BB] = tot / (1024.f * 1024.f);   // mean over B, then / B
    }
}

extern "C" void kernel_launch(void* const* d_in, const int* in_sizes, int n_in,
                              void* d_out, int out_size, void* d_ws, size_t ws_size,
                              hipStream_t stream) {
    const float* feature = (const float*)d_in[0];
    const float* text    = (const float*)d_in[1];
    const float* virt    = (const float*)d_in[2];
    const float* gumbel  = (const float*)d_in[3];
    const int*   ego     = (const int*)d_in[4];
    const int*   adj     = (const int*)d_in[5];
    const int*   label   = (const int*)d_in[6];
    float* out       = (float*)d_out;
    float* score_raw = (float*)d_ws;   // 1024 floats of scratch

    fused_main<<<BB, 512, 0, stream>>>(feature, text, virt, gumbel, ego, adj, score_raw);
    finalize<<<1, 1024, 0, stream>>>(score_raw, label, out);
}

// Round 2
// 76.095 us; speedup vs baseline: 1.0889x; 1.0889x over previous
//
#include <hip/hip_runtime.h>
#include <math.h>

#define DIM 256
#define BB 1024
#define KK 128
#define PITCH 264   // bf16 elements per LDS row: 528 B = 33*16

typedef __attribute__((ext_vector_type(8))) short short8;
typedef __attribute__((ext_vector_type(4))) float float4v;

__device__ __forceinline__ unsigned short f2bf(float x) {
    unsigned u = __float_as_uint(x);
    u += 0x7FFFu + ((u >> 16) & 1u);   // round-to-nearest-even
    return (unsigned short)(u >> 16);
}

__device__ __forceinline__ float dot4(const float4 a, const float4 b) {
    return a.x*b.x + a.y*b.y + a.z*b.z + a.w*b.w;
}

// One block per batch element. 512 threads = 8 waves.
__global__ __launch_bounds__(512, 4) void fused_main(
    const float* __restrict__ feature,
    const float* __restrict__ text,
    const float* __restrict__ virt,
    const float* __restrict__ gumbel,
    const int*   __restrict__ ego,
    const int*   __restrict__ adj,
    float*       __restrict__ score_raw)
{
    __shared__ unsigned short tbs[KK * PITCH];   // 67584 B
    __shared__ float fpart[8][DIM];              // 8192 B
    __shared__ float spart[8];

    const int b    = blockIdx.x;
    const int tid  = threadIdx.x;
    const int wave = tid >> 6;
    const int lane = tid & 63;

    const float4 vv = ((const float4*)virt)[lane];
    float vv2 = dot4(vv, vv);
    #pragma unroll
    for (int m = 1; m < 64; m <<= 1) vv2 += __shfl_xor(vv2, m);   // ||v||^2, all lanes

    const int* ego_b = ego + b * KK;
    const int  base  = wave * 16;

    float fd0 = 0.f, fd1 = 0.f, fd2 = 0.f, fd3 = 0.f;

    // ---- Phase A: gather + normalize, 2 rows/iter, loads pipelined 2 ahead.
    int ea = ego_b[base + 0], eb = ego_b[base + 1];
    float4 nta = ((const float4*)(text    + (size_t)ea * DIM))[lane];
    float4 nfa = ((const float4*)(feature + (size_t)ea * DIM))[lane];
    float4 ntb = ((const float4*)(text    + (size_t)eb * DIM))[lane];
    float4 nfb = ((const float4*)(feature + (size_t)eb * DIM))[lane];

    #pragma unroll
    for (int kk = 0; kk < 16; kk += 2) {
        const float4 at = nta, af = nfa, bt = ntb, bf = nfb;
        if (kk + 2 < 16) {
            const int na = ego_b[base + kk + 2], nb = ego_b[base + kk + 3];
            nta = ((const float4*)(text    + (size_t)na * DIM))[lane];
            nfa = ((const float4*)(feature + (size_t)na * DIM))[lane];
            ntb = ((const float4*)(text    + (size_t)nb * DIM))[lane];
            nfb = ((const float4*)(feature + (size_t)nb * DIM))[lane];
        }
        // one reduction tree for all six sums
        float sta = dot4(at, at), sfa = dot4(af, af), sva = dot4(at, vv);
        float stb = dot4(bt, bt), sfb = dot4(bf, bf), svb = dot4(bt, vv);
        #pragma unroll
        for (int m = 1; m < 64; m <<= 1) {
            sta += __shfl_xor(sta, m);  sfa += __shfl_xor(sfa, m);  sva += __shfl_xor(sva, m);
            stb += __shfl_xor(stb, m);  sfb += __shfl_xor(sfb, m);  svb += __shfl_xor(svb, m);
        }
        { // row kk
            const float inv_ne = 1.f / fmaxf(sqrtf(sta), 1e-12f);
            const float inv_nf = 1.f / fmaxf(sqrtf(sfa), 1e-12f);
            // ||emb - v||^2 = 1 - 2 (t.v)/||t|| + ||v||^2
            const float nw2    = fmaxf(1.f + vv2 - 2.f * sva * inv_ne, 0.f);
            const float inv_nt = 1.f / fmaxf(sqrtf(nw2), 1e-12f);
            const float ex = at.x*inv_ne, ey = at.y*inv_ne, ez = at.z*inv_ne, ew = at.w*inv_ne;
            fd0 += af.x*inv_nf - ex;  fd1 += af.y*inv_nf - ey;
            fd2 += af.z*inv_nf - ez;  fd3 += af.w*inv_nf - ew;
            ushort4 pk;
            pk.x = f2bf((ex - vv.x) * inv_nt);
            pk.y = f2bf((ey - vv.y) * inv_nt);
            pk.z = f2bf((ez - vv.z) * inv_nt);
            pk.w = f2bf((ew - vv.w) * inv_nt);
            *(ushort4*)&tbs[(base + kk) * PITCH + 4 * lane] = pk;
        }
        { // row kk+1
            const float inv_ne = 1.f / fmaxf(sqrtf(stb), 1e-12f);
            const float inv_nf = 1.f / fmaxf(sqrtf(sfb), 1e-12f);
            const float nw2    = fmaxf(1.f + vv2 - 2.f * svb * inv_ne, 0.f);
            const float inv_nt = 1.f / fmaxf(sqrtf(nw2), 1e-12f);
            const float ex = bt.x*inv_ne, ey = bt.y*inv_ne, ez = bt.z*inv_ne, ew = bt.w*inv_ne;
            fd0 += bf.x*inv_nf - ex;  fd1 += bf.y*inv_nf - ey;
            fd2 += bf.z*inv_nf - ez;  fd3 += bf.w*inv_nf - ew;
            ushort4 pk;
            pk.x = f2bf((ex - vv.x) * inv_nt);
            pk.y = f2bf((ey - vv.y) * inv_nt);
            pk.z = f2bf((ez - vv.z) * inv_nt);
            pk.w = f2bf((ew - vv.w) * inv_nt);
            *(ushort4*)&tbs[(base + kk + 1) * PITCH + 4 * lane] = pk;
        }
    }
    fpart[wave][4*lane + 0] = fd0;
    fpart[wave][4*lane + 1] = fd1;
    fpart[wave][4*lane + 2] = fd2;
    fpart[wave][4*lane + 3] = fd3;
    __syncthreads();

    // ---- Phase B: Gram matrix via MFMA; gumbel loads hoisted above the q-loop.
    const int g = lane >> 4;   // 0..3
    const int c = lane & 15;

    const float* gb = gumbel + (size_t)b * KK * KK;
    const int*   ab = adj    + (size_t)b * KK * KK;

    float gvv[32];
    #pragma unroll
    for (int r = 0; r < 4; ++r) {
        const float* gr = gb + (base + g*4 + r) * KK + c;
        #pragma unroll
        for (int t = 0; t < 8; ++t)
            gvv[r*8 + t] = __builtin_nontemporal_load(gr + t*16);
    }

    float4v acc[8];
    const float4v zero = {0.f, 0.f, 0.f, 0.f};
    #pragma unroll
    for (int t = 0; t < 8; ++t) acc[t] = zero;

    #pragma unroll
    for (int q = 0; q < 8; ++q) {
        const int dq = q * 32 + g * 8;
        const short8 afr = *(const short8*)&tbs[(base + c) * PITCH + dq];
        #pragma unroll
        for (int t = 0; t < 8; ++t) {
            const short8 bfr = *(const short8*)&tbs[(t*16 + c) * PITCH + dq];
            acc[t] = __builtin_amdgcn_mfma_f32_16x16x32_bf16(afr, bfr, acc[t], 0, 0, 0);
        }
    }

    int avv[32];
    #pragma unroll
    for (int r = 0; r < 4; ++r) {
        const int* ar = ab + (base + g*4 + r) * KK + c;
        #pragma unroll
        for (int t = 0; t < 8; ++t)
            avv[r*8 + t] = __builtin_nontemporal_load(ar + t*16);
    }

    // ---- softmax rows + s_diff: one 4-step tree per row.
    // No max-subtract needed: |sim-0.5+gumbel| <~ 14 -> exp safe in fp32.
    // sum (adj-p)^2 = sum(adj) - 2 invS sum(adj e) + invS^2 sum(e^2), p = e*invS
    float rs = 0.f;
    #pragma unroll
    for (int r = 0; r < 4; ++r) {
        float s = 0.f, a1 = 0.f, a2 = 0.f, a3 = 0.f;
        #pragma unroll
        for (int t = 0; t < 8; ++t) {
            const float vt = acc[t][r] - 0.5f + gvv[r*8 + t];
            const float et = __expf(vt);
            const float ad = (float)avv[r*8 + t];
            s  += et;
            a3 += et * et;
            a1 += ad;
            a2 += ad * et;
        }
        #pragma unroll
        for (int msk = 1; msk < 16; msk <<= 1) {
            s  += __shfl_xor(s,  msk);
            a1 += __shfl_xor(a1, msk);
            a2 += __shfl_xor(a2, msk);
            a3 += __shfl_xor(a3, msk);
        }
        const float invS = 1.f / s;
        const float T = a1 - 2.f * invS * a2 + invS * invS * a3;
        rs += sqrtf(fmaxf(T, 0.f));
    }
    rs += __shfl_xor(rs, 16);
    rs += __shfl_xor(rs, 32);          // 16-row strip total
    if (lane == 0) spart[wave] = rs;
    __syncthreads();

    if (wave == 0) {
        float d0 = 0.f, d1 = 0.f, d2 = 0.f, d3 = 0.f;
        #pragma unroll
        for (int w = 0; w < 8; ++w) {
            d0 += fpart[w][lane];
            d1 += fpart[w][lane + 64];
            d2 += fpart[w][lane + 128];
            d3 += fpart[w][lane + 192];
        }
        const float inv = 1.f / 128.f;
        d0 *= inv; d1 *= inv; d2 *= inv; d3 *= inv;
        float q2 = d0*d0 + d1*d1 + d2*d2 + d3*d3;
        #pragma unroll
        for (int m = 1; m < 64; m <<= 1) q2 += __shfl_xor(q2, m);
        if (lane == 0) {
            float stot = 0.f;
            #pragma unroll
            for (int w = 0; w < 8; ++w) stot += spart[w];
            score_raw[b] = stot * (1.f / 128.f) + sqrtf(q2);
        }
    }
}

__global__ __launch_bounds__(1024) void finalize(
    const float* __restrict__ score_raw,
    const int*   __restrict__ label,
    float*       __restrict__ out)
{
    __shared__ float wmin[16], wmax[16], wsum[16];
    const int tid = threadIdx.x;
    const float s = score_raw[tid];
    float mn = s, mx = s;
    #pragma unroll
    for (int m = 1; m < 64; m <<= 1) {
        mn = fminf(mn, __shfl_xor(mn, m));
        mx = fmaxf(mx, __shfl_xor(mx, m));
    }
    if ((tid & 63) == 0) { wmin[tid >> 6] = mn; wmax[tid >> 6] = mx; }
    __syncthreads();
    float gmn = wmin[0], gmx = wmax[0];
    #pragma unroll
    for (int w = 1; w < 16; ++w) {
        gmn = fminf(gmn, wmin[w]);
        gmx = fmaxf(gmx, wmax[w]);
    }
    const float score = (s - gmn) / (gmx - gmn);
    out[tid] = score;

    const float y  = (float)label[tid];
    const float sc = fminf(fmaxf(score, 1e-7f), 1.f - 1e-7f);
    float term = -(y * logf(sc) + (1.f - y) * log1pf(-sc));
    #pragma unroll
    for (int m = 1; m < 64; m <<= 1) term += __shfl_xor(term, m);
    if ((tid & 63) == 0) wsum[tid >> 6] = term;
    __syncthreads();
    if (tid == 0) {
        float tot = 0.f;
        #pragma unroll
        for (int w = 0; w < 16; ++w) tot += wsum[w];
        out[BB] = tot / (1024.f * 1024.f);
    }
}

extern "C" void kernel_launch(void* const* d_in, const int* in_sizes, int n_in,
                              void* d_out, int out_size, void* d_ws, size_t ws_size,
                              hipStream_t stream) {
    const float* feature = (const float*)d_in[0];
    const float* text    = (const float*)d_in[1];
    const float* virt    = (const float*)d_in[2];
    const float* gumbel  = (const float*)d_in[3];
    const int*   ego     = (const int*)d_in[4];
    const int*   adj     = (const int*)d_in[5];
    const int*   label   = (const int*)d_in[6];
    float* out       = (float*)d_out;
    float* score_raw = (float*)d_ws;

    fused_main<<<BB, 512, 0, stream>>>(feature, text, virt, gumbel, ego, adj, score_raw);
    finalize<<<1, 1024, 0, stream>>>(score_raw, label, out);
}